// Round 4
// baseline (130.681 us; speedup 1.0000x reference)
//
#include <hip/hip_runtime.h>
#include <math.h>

#define RESN 2048
#define TEXW 1024

// atan2 for y >= 0, returns [0, pi]. Cephes-style: min/max ratio + pi/8
// reduction + 4-term odd minimax + 1 Newton step on rcp. Peak err ~3e-7 rad.
__device__ __forceinline__ float fatan2_pos(float y, float x) {
    float ax = fabsf(x);
    float mn = fminf(ax, y);
    float mx = fmaxf(ax, y);
    float r0 = __builtin_amdgcn_rcpf(mx);
    r0 = r0 * __builtin_fmaf(-mx, r0, 2.0f);        // 1 Newton step -> ~0.5 ulp
    float a = mn * r0;                               // in [0,1]
    bool red = a > 0.41421356f;
    float t = (a - 1.0f) * __builtin_amdgcn_rcpf(a + 1.0f);
    float w = red ? t : a;                           // |w| <= 0.41421356
    float s = w * w;
    float p = __builtin_fmaf(s, 8.05374449538e-2f, -1.38776856032e-1f);
    p = __builtin_fmaf(s, p, 1.99777106478e-1f);
    p = __builtin_fmaf(s, p, -3.33329491539e-1f);
    float r = __builtin_fmaf(w * s, p, w);           // atan(w)
    r = red ? r + 0.78539816339f : r;                // + pi/4
    r = (y > ax) ? 1.57079632679f - r : r;
    r = (x < 0.0f) ? 3.14159265359f - r : r;
    return r;
}

__device__ __forceinline__ void store3_nt(float* p, float a, float b, float c) {
    __builtin_nontemporal_store(a, p + 0);
    __builtin_nontemporal_store(b, p + 1);
    __builtin_nontemporal_store(c, p + 2);
}

__global__ __launch_bounds__(256, 8) void egg_render(
    const float* __restrict__ tex,
    const float* __restrict__ nmap,
    float* __restrict__ out)
{
    int t = blockIdx.x * 256 + threadIdx.x;      // one thread = 4 consecutive pixels in a row
    int j = t >> 9;                              // row
    int i0 = (t & 511) << 2;                     // column base
    float* obase = out + (size_t)t * 12u;

    const float invres = 1.0f / (float)RESN;
    // bit-exact vs numpy on the inside-test path: no fma contraction
    float ny = __fmul_rn(__fsub_rn(0.5f, __fmul_rn((float)j, invres)), 2.0f) / 0.85f;
    float nysq = __fmul_rn(ny, ny);

    if (!(nysq <= 1.0f)) {                       // whole row outside the disc
        #pragma unroll
        for (int k = 0; k < 4; ++k) store3_nt(obase + k * 3, 0.f, 0.f, 0.f);
        return;
    }

    // ---- row-shared work (ny-only dependent) ----
    float egg = 1.0f - 0.25f * ny;               // in [0.75, 1.25] inside the disc
    float sphi = sqrtf(fmaxf(__builtin_fmaf(-ny, ny, 1.0f), 0.0f));
    float phi = fatan2_pos(sphi, ny);            // == acos(ny)
    float v = phi * 0.3183098861837907f;         // /pi
    v -= floorf(v);
    float yy = v * (float)TEXW - 0.5f;
    float yf = floorf(yy);
    float fy = yy - yf;
    float gy = 1.0f - fy;
    int y0 = (int)yf & (TEXW - 1);
    int y1 = (y0 + 1) & (TEXW - 1);
    int rb0 = y0 * TEXW;
    int rb1 = y1 * TEXW;

    // lighting constants (compile-time folded, f32 semantics)
    float Lx = 0.5f, Ly = 0.7f, Lz = 1.0f;
    float ll = sqrtf(Lx * Lx + Ly * Ly + Lz * Lz);
    Lx /= ll; Ly /= ll; Lz /= ll;
    float Hx = Lx, Hy = Ly, Hz = Lz + 1.0f;
    float hl = sqrtf(Hx * Hx + Hy * Hy + Hz * Hz);
    Hx /= hl; Hy /= hl; Hz /= hl;

    #pragma unroll 1                             // keep VGPRs low -> 8 waves/SIMD
    for (int k = 0; k < 4; ++k) {
        float nx = __fmul_rn(__fsub_rn(__fmul_rn((float)(i0 + k), invres), 0.5f), 2.0f) / 0.85f;
        float rsq = __fadd_rn(__fmul_rn(nx, nx), nysq);
        if (!(rsq <= 1.0f)) {
            store3_nt(obase + k * 3, 0.f, 0.f, 0.f);
            continue;
        }

        float z = sqrtf(fmaxf(__fsub_rn(1.0f, rsq), 0.0f));

        // atan2(z/egg, nx/egg) == atan2(z, nx): egg > 0 inside the disc
        float theta = fatan2_pos(z, nx);
        float u = theta * 0.15915494309189535f + 0.5f;   // /(2pi)
        u -= floorf(u);

        // x-side bilinear (y-side shared per row)
        float xx = u * (float)TEXW - 0.5f;
        float xf = floorf(xx);
        float fx = xx - xf;
        float gx = 1.0f - fx;
        int x0 = (int)xf & (TEXW - 1);
        int x1 = (x0 + 1) & (TEXW - 1);
        float w00 = gx * gy, w01 = fx * gy, w10 = gx * fy, w11 = fx * fy;
        int o00 = (rb0 + x0) * 3;
        int o01 = (rb0 + x1) * 3;
        int o10 = (rb1 + x0) * 3;
        int o11 = (rb1 + x1) * 3;

        // corner-by-corner accumulation: only 6 texels live at a time
        float ar, ag, ab, tnx, tny, tnz;
        {
            ar  = tex[o00+0] * w00; ag  = tex[o00+1] * w00; ab  = tex[o00+2] * w00;
            tnx = nmap[o00+0] * w00; tny = nmap[o00+1] * w00; tnz = nmap[o00+2] * w00;
        }
        {
            ar  = __builtin_fmaf(tex[o01+0], w01, ar);  ag  = __builtin_fmaf(tex[o01+1], w01, ag);  ab  = __builtin_fmaf(tex[o01+2], w01, ab);
            tnx = __builtin_fmaf(nmap[o01+0], w01, tnx); tny = __builtin_fmaf(nmap[o01+1], w01, tny); tnz = __builtin_fmaf(nmap[o01+2], w01, tnz);
        }
        {
            ar  = __builtin_fmaf(tex[o10+0], w10, ar);  ag  = __builtin_fmaf(tex[o10+1], w10, ag);  ab  = __builtin_fmaf(tex[o10+2], w10, ab);
            tnx = __builtin_fmaf(nmap[o10+0], w10, tnx); tny = __builtin_fmaf(nmap[o10+1], w10, tny); tnz = __builtin_fmaf(nmap[o10+2], w10, tnz);
        }
        {
            ar  = __builtin_fmaf(tex[o11+0], w11, ar);  ag  = __builtin_fmaf(tex[o11+1], w11, ag);  ab  = __builtin_fmaf(tex[o11+2], w11, ab);
            tnx = __builtin_fmaf(nmap[o11+0], w11, tnx); tny = __builtin_fmaf(nmap[o11+1], w11, tny); tnz = __builtin_fmaf(nmap[o11+2], w11, tnz);
        }
        tnx = tnx * 2.0f - 1.0f;
        tny = tny * 2.0f - 1.0f;
        tnz = tnz * 2.0f - 1.0f;

        // analytical egg normal (|sn|^2 >= 0.5625 inside the disc)
        float snx = nx * egg, sny = ny, snz = z * egg;
        float sl2 = snx*snx + sny*sny + snz*snz;
        float isl = __builtin_amdgcn_rsqf(sl2);
        float bnx = snx * isl, bny = sny * isl, bnz = snz * isl;

        // Gram-Schmidt TBN (|t|^2 >= 0.0199)
        bool use_right = fabsf(bny) > 0.99f;
        float rx = use_right ? 1.0f : 0.0f;
        float ry = use_right ? 0.0f : 1.0f;
        float d  = use_right ? bnx : bny;
        float tx = rx - d * bnx;
        float ty = ry - d * bny;
        float tz = -d * bnz;
        float tl2 = tx*tx + ty*ty + tz*tz;
        float itl = __builtin_amdgcn_rsqf(tl2);
        tx *= itl; ty *= itl; tz *= itl;
        float bxx = bny * tz - bnz * ty;
        float bxy = bnz * tx - bnx * tz;
        float bxz = bnx * ty - bny * tx;

        // perturbed normal; BUMP_STRENGTH = 1 -> nrm = normalize(world_n)
        float wx = tnx * tx + tny * bxx + tnz * bnx;
        float wy = tnx * ty + tny * bxy + tnz * bny;
        float wz = tnx * tz + tny * bxz + tnz * bnz;
        float wl2 = wx*wx + wy*wy + wz*wz;
        float iwl = __builtin_amdgcn_rsqf(fmaxf(wl2, 1e-12f));
        wx *= iwl; wy *= iwl; wz *= iwl;

        float ndotl = fmaxf(wx * Lx + wy * Ly + wz * Lz, 0.0f);
        float ndoth = fmaxf(wx * Hx + wy * Hy + wz * Hz, 0.0f);
        float s2 = ndoth * ndoth, s4 = s2 * s2, s8 = s4 * s4, s16 = s8 * s8;
        float spec = s16 * s16;                   // ndoth^32
        float ndotv = fmaxf(wz, 0.0f);
        float t1 = 1.0f - ndotv;
        float t2 = t1 * t1, t4 = t2 * t2;
        float fres = 0.04f + 0.96f * (t4 * t1);   // Schlick, F0=0.04
        float ka = 0.1f + ndotl;
        float add = spec * fres;

        store3_nt(obase + k * 3,
                  fminf(fmaxf(__builtin_fmaf(ar, ka, add), 0.0f), 1.0f),
                  fminf(fmaxf(__builtin_fmaf(ag, ka, add), 0.0f), 1.0f),
                  fminf(fmaxf(__builtin_fmaf(ab, ka, add), 0.0f), 1.0f));
    }
}

extern "C" void kernel_launch(void* const* d_in, const int* in_sizes, int n_in,
                              void* d_out, int out_size, void* d_ws, size_t ws_size,
                              hipStream_t stream) {
    const float* tex  = (const float*)d_in[0];
    const float* nmap = (const float*)d_in[1];
    float* out = (float*)d_out;
    int total_threads = RESN * RESN / 4;          // 1,048,576
    dim3 grid(total_threads / 256), block(256);   // 4096 blocks
    hipLaunchKernelGGL(egg_render, grid, block, 0, stream, tex, nmap, out);
}

// Round 5
// 37.519 us; speedup vs baseline: 3.4831x; 3.4831x over previous
//
#include <hip/hip_runtime.h>
#include <math.h>

#define RESN 2048
#define TEXW 1024

// atan2 for y >= 0, returns [0, pi]. Cephes-style: min/max ratio + pi/8
// reduction + 4-term odd minimax + 1 Newton step on rcp. Peak err ~3e-7 rad.
__device__ __forceinline__ float fatan2_pos(float y, float x) {
    float ax = fabsf(x);
    float mn = fminf(ax, y);
    float mx = fmaxf(ax, y);
    float r0 = __builtin_amdgcn_rcpf(mx);
    r0 = r0 * __builtin_fmaf(-mx, r0, 2.0f);        // 1 Newton step -> ~0.5 ulp
    float a = mn * r0;                               // in [0,1]
    bool red = a > 0.41421356f;
    float t = (a - 1.0f) * __builtin_amdgcn_rcpf(a + 1.0f);
    float w = red ? t : a;                           // |w| <= 0.41421356
    float s = w * w;
    float p = __builtin_fmaf(s, 8.05374449538e-2f, -1.38776856032e-1f);
    p = __builtin_fmaf(s, p, 1.99777106478e-1f);
    p = __builtin_fmaf(s, p, -3.33329491539e-1f);
    float r = __builtin_fmaf(w * s, p, w);           // atan(w)
    r = red ? r + 0.78539816339f : r;                // + pi/4
    r = (y > ax) ? 1.57079632679f - r : r;
    r = (x < 0.0f) ? 3.14159265359f - r : r;
    return r;
}

// plain (cached) stores: L2 write-combines the 48B-stride lane pattern to
// exactly 50 MB of HBM writes (R0 evidence). NT stores amplified 5.3x (R3).
__device__ __forceinline__ void store3(float* p, float a, float b, float c) {
    p[0] = a; p[1] = b; p[2] = c;
}

__global__ __launch_bounds__(256, 8) void egg_render(
    const float* __restrict__ tex,
    const float* __restrict__ nmap,
    float* __restrict__ out)
{
    int t = blockIdx.x * 256 + threadIdx.x;      // one thread = 4 consecutive pixels in a row
    int j = t >> 9;                              // row
    int i0 = (t & 511) << 2;                     // column base
    float* obase = out + (size_t)t * 12u;

    const float invres = 1.0f / (float)RESN;
    // bit-exact vs numpy on the inside-test path: no fma contraction
    float ny = __fmul_rn(__fsub_rn(0.5f, __fmul_rn((float)j, invres)), 2.0f) / 0.85f;
    float nysq = __fmul_rn(ny, ny);

    if (!(nysq <= 1.0f)) {                       // whole row outside the disc
        #pragma unroll
        for (int k = 0; k < 4; ++k) store3(obase + k * 3, 0.f, 0.f, 0.f);
        return;
    }

    // ---- row-shared work (ny-only dependent) ----
    float egg = 1.0f - 0.25f * ny;               // in [0.75, 1.25] inside the disc
    float sphi = sqrtf(fmaxf(__builtin_fmaf(-ny, ny, 1.0f), 0.0f));
    float phi = fatan2_pos(sphi, ny);            // == acos(ny)
    float v = phi * 0.3183098861837907f;         // /pi
    v -= floorf(v);
    float yy = v * (float)TEXW - 0.5f;
    float yf = floorf(yy);
    float fy = yy - yf;
    float gy = 1.0f - fy;
    int y0 = (int)yf & (TEXW - 1);
    int y1 = (y0 + 1) & (TEXW - 1);
    int rb0 = y0 * TEXW;
    int rb1 = y1 * TEXW;

    // lighting constants (compile-time folded, f32 semantics)
    float Lx = 0.5f, Ly = 0.7f, Lz = 1.0f;
    float ll = sqrtf(Lx * Lx + Ly * Ly + Lz * Lz);
    Lx /= ll; Ly /= ll; Lz /= ll;
    float Hx = Lx, Hy = Ly, Hz = Lz + 1.0f;
    float hl = sqrtf(Hx * Hx + Hy * Hy + Hz * Hz);
    Hx /= hl; Hy /= hl; Hz /= hl;

    #pragma unroll 1                             // keep VGPRs low (32) -> high occupancy
    for (int k = 0; k < 4; ++k) {
        float nx = __fmul_rn(__fsub_rn(__fmul_rn((float)(i0 + k), invres), 0.5f), 2.0f) / 0.85f;
        float rsq = __fadd_rn(__fmul_rn(nx, nx), nysq);
        if (!(rsq <= 1.0f)) {
            store3(obase + k * 3, 0.f, 0.f, 0.f);
            continue;
        }

        float z = sqrtf(fmaxf(__fsub_rn(1.0f, rsq), 0.0f));

        // atan2(z/egg, nx/egg) == atan2(z, nx): egg > 0 inside the disc
        float theta = fatan2_pos(z, nx);
        float u = theta * 0.15915494309189535f + 0.5f;   // /(2pi)
        u -= floorf(u);

        // x-side bilinear (y-side shared per row)
        float xx = u * (float)TEXW - 0.5f;
        float xf = floorf(xx);
        float fx = xx - xf;
        float gx = 1.0f - fx;
        int x0 = (int)xf & (TEXW - 1);
        int x1 = (x0 + 1) & (TEXW - 1);
        float w00 = gx * gy, w01 = fx * gy, w10 = gx * fy, w11 = fx * fy;
        int o00 = (rb0 + x0) * 3;
        int o01 = (rb0 + x1) * 3;
        int o10 = (rb1 + x0) * 3;
        int o11 = (rb1 + x1) * 3;

        // corner-by-corner accumulation: only 6 texels live at a time
        float ar  = tex[o00+0] * w00, ag  = tex[o00+1] * w00, ab  = tex[o00+2] * w00;
        float tnx = nmap[o00+0] * w00, tny = nmap[o00+1] * w00, tnz = nmap[o00+2] * w00;

        ar  = __builtin_fmaf(tex[o01+0], w01, ar);  ag  = __builtin_fmaf(tex[o01+1], w01, ag);  ab  = __builtin_fmaf(tex[o01+2], w01, ab);
        tnx = __builtin_fmaf(nmap[o01+0], w01, tnx); tny = __builtin_fmaf(nmap[o01+1], w01, tny); tnz = __builtin_fmaf(nmap[o01+2], w01, tnz);

        ar  = __builtin_fmaf(tex[o10+0], w10, ar);  ag  = __builtin_fmaf(tex[o10+1], w10, ag);  ab  = __builtin_fmaf(tex[o10+2], w10, ab);
        tnx = __builtin_fmaf(nmap[o10+0], w10, tnx); tny = __builtin_fmaf(nmap[o10+1], w10, tny); tnz = __builtin_fmaf(nmap[o10+2], w10, tnz);

        ar  = __builtin_fmaf(tex[o11+0], w11, ar);  ag  = __builtin_fmaf(tex[o11+1], w11, ag);  ab  = __builtin_fmaf(tex[o11+2], w11, ab);
        tnx = __builtin_fmaf(nmap[o11+0], w11, tnx); tny = __builtin_fmaf(nmap[o11+1], w11, tny); tnz = __builtin_fmaf(nmap[o11+2], w11, tnz);

        tnx = tnx * 2.0f - 1.0f;
        tny = tny * 2.0f - 1.0f;
        tnz = tnz * 2.0f - 1.0f;

        // analytical egg normal (|sn|^2 >= 0.5625 inside the disc)
        float snx = nx * egg, sny = ny, snz = z * egg;
        float sl2 = snx*snx + sny*sny + snz*snz;
        float isl = __builtin_amdgcn_rsqf(sl2);
        float bnx = snx * isl, bny = sny * isl, bnz = snz * isl;

        // Gram-Schmidt TBN (|t|^2 >= 0.0199)
        bool use_right = fabsf(bny) > 0.99f;
        float rx = use_right ? 1.0f : 0.0f;
        float ry = use_right ? 0.0f : 1.0f;
        float d  = use_right ? bnx : bny;
        float tx = rx - d * bnx;
        float ty = ry - d * bny;
        float tz = -d * bnz;
        float tl2 = tx*tx + ty*ty + tz*tz;
        float itl = __builtin_amdgcn_rsqf(tl2);
        tx *= itl; ty *= itl; tz *= itl;
        float bxx = bny * tz - bnz * ty;
        float bxy = bnz * tx - bnx * tz;
        float bxz = bnx * ty - bny * tx;

        // perturbed normal; BUMP_STRENGTH = 1 -> nrm = normalize(world_n)
        float wx = tnx * tx + tny * bxx + tnz * bnx;
        float wy = tnx * ty + tny * bxy + tnz * bny;
        float wz = tnx * tz + tny * bxz + tnz * bnz;
        float wl2 = wx*wx + wy*wy + wz*wz;
        float iwl = __builtin_amdgcn_rsqf(fmaxf(wl2, 1e-12f));
        wx *= iwl; wy *= iwl; wz *= iwl;

        float ndotl = fmaxf(wx * Lx + wy * Ly + wz * Lz, 0.0f);
        float ndoth = fmaxf(wx * Hx + wy * Hy + wz * Hz, 0.0f);
        float s2 = ndoth * ndoth, s4 = s2 * s2, s8 = s4 * s4, s16 = s8 * s8;
        float spec = s16 * s16;                   // ndoth^32
        float ndotv = fmaxf(wz, 0.0f);
        float t1 = 1.0f - ndotv;
        float t2 = t1 * t1, t4 = t2 * t2;
        float fres = 0.04f + 0.96f * (t4 * t1);   // Schlick, F0=0.04
        float ka = 0.1f + ndotl;
        float add = spec * fres;

        store3(obase + k * 3,
               fminf(fmaxf(__builtin_fmaf(ar, ka, add), 0.0f), 1.0f),
               fminf(fmaxf(__builtin_fmaf(ag, ka, add), 0.0f), 1.0f),
               fminf(fmaxf(__builtin_fmaf(ab, ka, add), 0.0f), 1.0f));
    }
}

extern "C" void kernel_launch(void* const* d_in, const int* in_sizes, int n_in,
                              void* d_out, int out_size, void* d_ws, size_t ws_size,
                              hipStream_t stream) {
    const float* tex  = (const float*)d_in[0];
    const float* nmap = (const float*)d_in[1];
    float* out = (float*)d_out;
    int total_threads = RESN * RESN / 4;          // 1,048,576
    dim3 grid(total_threads / 256), block(256);   // 4096 blocks
    hipLaunchKernelGGL(egg_render, grid, block, 0, stream, tex, nmap, out);
}

// Round 6
// 28.795 us; speedup vs baseline: 4.5382x; 1.3029x over previous
//
#include <hip/hip_runtime.h>
#include <math.h>

#define RESN 2048
#define TEXW 1024

// atan2 for y >= 0, returns [0, pi]. Cephes-style: min/max ratio + pi/8
// reduction + 4-term odd minimax + 1 Newton step on rcp. Peak err ~3e-7 rad.
__device__ __forceinline__ float fatan2_pos(float y, float x) {
    float ax = fabsf(x);
    float mn = fminf(ax, y);
    float mx = fmaxf(ax, y);
    float r0 = __builtin_amdgcn_rcpf(mx);
    r0 = r0 * __builtin_fmaf(-mx, r0, 2.0f);        // 1 Newton step -> ~0.5 ulp
    float a = mn * r0;                               // in [0,1]
    bool red = a > 0.41421356f;
    float t = (a - 1.0f) * __builtin_amdgcn_rcpf(a + 1.0f);
    float w = red ? t : a;                           // |w| <= 0.41421356
    float s = w * w;
    float p = __builtin_fmaf(s, 8.05374449538e-2f, -1.38776856032e-1f);
    p = __builtin_fmaf(s, p, 1.99777106478e-1f);
    p = __builtin_fmaf(s, p, -3.33329491539e-1f);
    float r = __builtin_fmaf(w * s, p, w);           // atan(w)
    r = red ? r + 0.78539816339f : r;                // + pi/4
    r = (y > ax) ? 1.57079632679f - r : r;
    r = (x < 0.0f) ? 3.14159265359f - r : r;
    return r;
}

// 12-byte texel: compiler merges to global_load_dwordx3 (4B-aligned, exact
// 12B -> never reads past the last texel of the 12MB buffer)
struct __align__(4) F3 { float x, y, z; };

__global__ __launch_bounds__(256, 8) void egg_render(
    const float* __restrict__ tex,
    const float* __restrict__ nmap,
    float* __restrict__ out)
{
    // 1 px/thread: lanes 1 px apart -> minimal texel span per wave-gather
    // (~6 lines/instr vs ~24 at 4px/thread); 12B/lane contiguous stores
    // cover whole 64B lines per wave in one burst (WRITE_SIZE stays 50MB).
    int p = blockIdx.x * 256 + threadIdx.x;
    int i = p & (RESN - 1);
    int j = p >> 11;
    float* o = out + (size_t)p * 3u;

    const float invres = 1.0f / (float)RESN;
    // bit-exact vs numpy on the inside-test path: no fma contraction
    float nx = __fmul_rn(__fsub_rn(__fmul_rn((float)i, invres), 0.5f), 2.0f) / 0.85f;
    float ny = __fmul_rn(__fsub_rn(0.5f, __fmul_rn((float)j, invres)), 2.0f) / 0.85f;
    float rsq = __fadd_rn(__fmul_rn(nx, nx), __fmul_rn(ny, ny));
    if (!(rsq <= 1.0f)) {
        o[0] = 0.0f; o[1] = 0.0f; o[2] = 0.0f;
        return;
    }

    float z = sqrtf(fmaxf(__fsub_rn(1.0f, rsq), 0.0f));
    float egg = 1.0f - 0.25f * ny;               // in [0.75, 1.25] inside the disc

    // phi = acos(ny) via atan2(sqrt(1-ny^2), ny); fma keeps 1-ny^2 single-rounded
    float sphi = sqrtf(fmaxf(__builtin_fmaf(-ny, ny, 1.0f), 0.0f));
    float phi = fatan2_pos(sphi, ny);
    float v = phi * 0.3183098861837907f;         // /pi
    v -= floorf(v);

    // atan2(z/egg, nx/egg) == atan2(z, nx): egg > 0 inside the disc
    float theta = fatan2_pos(z, nx);
    float u = theta * 0.15915494309189535f + 0.5f;   // /(2pi)
    u -= floorf(u);

    // bilinear setup (wrap)
    float yy = v * (float)TEXW - 0.5f;
    float yf = floorf(yy);
    float fy = yy - yf;
    float gy = 1.0f - fy;
    int y0 = (int)yf & (TEXW - 1);
    int y1 = (y0 + 1) & (TEXW - 1);
    float xx = u * (float)TEXW - 0.5f;
    float xf = floorf(xx);
    float fx = xx - xf;
    float gx = 1.0f - fx;
    int x0 = (int)xf & (TEXW - 1);
    int x1 = (x0 + 1) & (TEXW - 1);
    float w00 = gx * gy, w01 = fx * gy, w10 = gx * fy, w11 = fx * fy;
    int o00 = (y0 * TEXW + x0) * 3;
    int o01 = (y0 * TEXW + x1) * 3;
    int o10 = (y1 * TEXW + x0) * 3;
    int o11 = (y1 * TEXW + x1) * 3;

    F3 a00 = *(const F3*)(tex + o00);
    F3 a01 = *(const F3*)(tex + o01);
    F3 a10 = *(const F3*)(tex + o10);
    F3 a11 = *(const F3*)(tex + o11);
    F3 n00 = *(const F3*)(nmap + o00);
    F3 n01 = *(const F3*)(nmap + o01);
    F3 n10 = *(const F3*)(nmap + o10);
    F3 n11 = *(const F3*)(nmap + o11);

    float ar = a00.x*w00 + a01.x*w01 + a10.x*w10 + a11.x*w11;
    float ag = a00.y*w00 + a01.y*w01 + a10.y*w10 + a11.y*w11;
    float ab = a00.z*w00 + a01.z*w01 + a10.z*w10 + a11.z*w11;
    float tnx = (n00.x*w00 + n01.x*w01 + n10.x*w10 + n11.x*w11) * 2.0f - 1.0f;
    float tny = (n00.y*w00 + n01.y*w01 + n10.y*w10 + n11.y*w11) * 2.0f - 1.0f;
    float tnz = (n00.z*w00 + n01.z*w01 + n10.z*w10 + n11.z*w11) * 2.0f - 1.0f;

    // analytical egg normal (|sn|^2 >= 0.5625 inside the disc)
    float snx = nx * egg, sny = ny, snz = z * egg;
    float sl2 = snx*snx + sny*sny + snz*snz;
    float isl = __builtin_amdgcn_rsqf(sl2);
    float bnx = snx * isl, bny = sny * isl, bnz = snz * isl;

    // Gram-Schmidt TBN (|t|^2 >= 0.0199)
    bool use_right = fabsf(bny) > 0.99f;
    float rx = use_right ? 1.0f : 0.0f;
    float ry = use_right ? 0.0f : 1.0f;
    float d  = use_right ? bnx : bny;
    float tx = rx - d * bnx;
    float ty = ry - d * bny;
    float tz = -d * bnz;
    float tl2 = tx*tx + ty*ty + tz*tz;
    float itl = __builtin_amdgcn_rsqf(tl2);
    tx *= itl; ty *= itl; tz *= itl;
    float bxx = bny * tz - bnz * ty;
    float bxy = bnz * tx - bnx * tz;
    float bxz = bnx * ty - bny * tx;

    // perturbed normal; BUMP_STRENGTH = 1 -> nrm = normalize(world_n)
    float wx = tnx * tx + tny * bxx + tnz * bnx;
    float wy = tnx * ty + tny * bxy + tnz * bny;
    float wz = tnx * tz + tny * bxz + tnz * bnz;
    float wl2 = wx*wx + wy*wy + wz*wz;
    float iwl = __builtin_amdgcn_rsqf(fmaxf(wl2, 1e-12f));
    wx *= iwl; wy *= iwl; wz *= iwl;

    // lighting constants (compile-time folded, f32 semantics)
    float Lx = 0.5f, Ly = 0.7f, Lz = 1.0f;
    float ll = sqrtf(Lx * Lx + Ly * Ly + Lz * Lz);
    Lx /= ll; Ly /= ll; Lz /= ll;
    float Hx = Lx, Hy = Ly, Hz = Lz + 1.0f;
    float hl = sqrtf(Hx * Hx + Hy * Hy + Hz * Hz);
    Hx /= hl; Hy /= hl; Hz /= hl;

    float ndotl = fmaxf(wx * Lx + wy * Ly + wz * Lz, 0.0f);
    float ndoth = fmaxf(wx * Hx + wy * Hy + wz * Hz, 0.0f);
    float s2 = ndoth * ndoth, s4 = s2 * s2, s8 = s4 * s4, s16 = s8 * s8;
    float spec = s16 * s16;                   // ndoth^32
    float ndotv = fmaxf(wz, 0.0f);
    float t1 = 1.0f - ndotv;
    float t2 = t1 * t1, t4 = t2 * t2;
    float fres = 0.04f + 0.96f * (t4 * t1);   // Schlick, F0=0.04
    float ka = 0.1f + ndotl;
    float add = spec * fres;

    // 3 adjacent dword stores -> dwordx3; wave covers 768B contiguous at once
    o[0] = fminf(fmaxf(__builtin_fmaf(ar, ka, add), 0.0f), 1.0f);
    o[1] = fminf(fmaxf(__builtin_fmaf(ag, ka, add), 0.0f), 1.0f);
    o[2] = fminf(fmaxf(__builtin_fmaf(ab, ka, add), 0.0f), 1.0f);
}

extern "C" void kernel_launch(void* const* d_in, const int* in_sizes, int n_in,
                              void* d_out, int out_size, void* d_ws, size_t ws_size,
                              hipStream_t stream) {
    const float* tex  = (const float*)d_in[0];
    const float* nmap = (const float*)d_in[1];
    float* out = (float*)d_out;
    int total = RESN * RESN;                      // 1 px/thread
    dim3 grid(total / 256), block(256);           // 16384 blocks
    hipLaunchKernelGGL(egg_render, grid, block, 0, stream, tex, nmap, out);
}